// Round 6
// baseline (546.754 us; speedup 1.0000x reference)
//
#include <hip/hip_runtime.h>
#include <hip/hip_fp16.h>
#include <math.h>

// KnowledgeLayer: encode -> product -> sum(lse) -> product -> sum(lse)
// csr is repeat(arange(M),4): each output node is an independent 4-gather reduce.
//
// R1: fp32 tables -> 269 MB fetch/layer (gather line amplification).
// R3: fp16 tables (L2-resident) + nt streams -> 38.5 MB/layer, 45 us/layer,
//     1 TB/s, VALU 10% => gather-transaction-bound (~0.29 line-req/cyc/CU,
//     matches L1 miss-queue cap: ~64 misses x ~220 cyc L2 latency).
// R4: 4 elem/thread (16 outstanding gathers) -> worse => not latency-bound.
// R5: cooperative grid.sync fusion -> broken under graph capture + slow. Dead end.
// R6: R3 structure + NT hint on the gather loads themselves (L1 bypass test).

#define LOG2F 0.6931471805599453f

typedef int iv4 __attribute__((ext_vector_type(4)));

// gather one fp16 table entry with non-temporal (L1-bypass) hint
__device__ __forceinline__ float gather_nt(const __half* __restrict__ x, int idx) {
    short s = __builtin_nontemporal_load((const short*)x + idx);
    return __half2float(__ushort_as_half((unsigned short)s));
}

__global__ void encode_kernel(const float* __restrict__ pos,
                              __half* __restrict__ x0, int n) {
    int i = blockIdx.x * blockDim.x + threadIdx.x;
    if (i == 0) { x0[0] = __float2half(-INFINITY); x0[1] = __float2half(0.0f); }
    if (i < n) {
        float p = pos[i];
        // log1mexp (Maechler 2012), stable for p < 0
        float neg = (p > -LOG2F) ? logf(-expm1f(p)) : log1pf(-expf(p));
        __half2 v; v.x = __float2half(p); v.y = __float2half(neg);
        ((__half2*)(x0 + 2))[i] = v;  // interleaved pos/neg
    }
}

__global__ void product_kernel(const __half* __restrict__ x,
                               const iv4* __restrict__ ptrs,
                               __half* __restrict__ out, int m) {
    int i = blockIdx.x * blockDim.x + threadIdx.x;
    if (i < m) {
        iv4 q = __builtin_nontemporal_load(&ptrs[i]);  // idx stream: touched once
        float s = gather_nt(x, q.x) + gather_nt(x, q.y)
                + gather_nt(x, q.z) + gather_nt(x, q.w);
        __builtin_nontemporal_store(__half_as_short(__float2half(s)),
                                    (short*)&out[i]);
    }
}

__device__ __forceinline__ float lse4(float a, float b, float c, float d) {
    float mx = fmaxf(fmaxf(a, b), fmaxf(c, d));
    if (mx == -INFINITY) return -INFINITY;  // ref: exps nan->0, log(eps)+(-inf)
    float s = expf(a - mx) + expf(b - mx) + expf(c - mx) + expf(d - mx) + 1e-15f;
    return logf(s) + mx;
}

template <typename OutT>
__global__ void sum_kernel(const __half* __restrict__ x,
                           const iv4* __restrict__ ptrs,
                           OutT* __restrict__ out, int m) {
    int i = blockIdx.x * blockDim.x + threadIdx.x;
    if (i < m) {
        iv4 q = __builtin_nontemporal_load(&ptrs[i]);
        float a = gather_nt(x, q.x), b = gather_nt(x, q.y);
        float c = gather_nt(x, q.z), d = gather_nt(x, q.w);
        float r = lse4(a, b, c, d);
        if constexpr (sizeof(OutT) == 2) {
            __builtin_nontemporal_store(__half_as_short(__float2half(r)),
                                        (short*)&out[i]);
        } else {
            __builtin_nontemporal_store(r, (float*)&out[i]);
        }
    }
}

extern "C" void kernel_launch(void* const* d_in, const int* in_sizes, int n_in,
                              void* d_out, int out_size, void* d_ws, size_t ws_size,
                              hipStream_t stream) {
    const float* pos = (const float*)d_in[0];
    const iv4*   p0  = (const iv4*)d_in[1];
    const iv4*   p1  = (const iv4*)d_in[2];
    const iv4*   p2  = (const iv4*)d_in[3];
    const iv4*   p3  = (const iv4*)d_in[4];
    // d_in[5] is csr — structurally repeat(arange(M),4), not needed.

    const int N = in_sizes[0];      // 1,000,000
    const int M = out_size;         // 2,000,000

    char* ws = (char*)d_ws;
    size_t s0_bytes = ((((size_t)2 * N + 2) * sizeof(__half)) + 255) & ~(size_t)255;
    size_t m_bytes  = (((size_t)M * sizeof(__half)) + 255) & ~(size_t)255;
    __half* x0 = (__half*)ws;                          // encoded input [2N+2] fp16
    __half* x1 = (__half*)(ws + s0_bytes);             // layer scratch [M] fp16
    __half* x2 = (__half*)(ws + s0_bytes + m_bytes);   // layer scratch [M] fp16
    float* outp = (float*)d_out;                       // final output fp32

    const int blk = 256;
    const int gN = (N + blk - 1) / blk;
    const int gM = (M + blk - 1) / blk;

    encode_kernel     <<<gN, blk, 0, stream>>>(pos, x0, N);
    product_kernel    <<<gM, blk, 0, stream>>>(x0, p0, x1, M);
    sum_kernel<__half><<<gM, blk, 0, stream>>>(x1, p1, x2, M);
    product_kernel    <<<gM, blk, 0, stream>>>(x2, p2, x1, M);
    sum_kernel<float> <<<gM, blk, 0, stream>>>(x1, p3, outp, M);
}

// Round 7
// 306.547 us; speedup vs baseline: 1.7836x; 1.7836x over previous
//
#include <hip/hip_runtime.h>
#include <hip/hip_fp16.h>
#include <math.h>

// KnowledgeLayer: encode -> product -> sum(lse) -> product -> sum(lse)
// csr is repeat(arange(M),4): each output node is an independent 4-gather reduce.
//
// R1: fp32 tables -> 269 MB fetch/layer (gather line amplification).
// R3: fp16 tables (L2-resident) + nt idx/store streams -> 38.5 MB/layer,
//     45 us/layer. Model: per-CU line fills ~31250/layer, t = lines*lat/MSHR
//     = 31250*220/64 = 45 us. MATCHES.
// R4: 4 elem/thread -> worse => MSHR(=64)-bound, not wave-latency-bound.
// R5: cooperative fusion -> broken under graph capture. Dead end.
// R6: nt on gathers -> bypasses L2 alloc, gathers hit L3 (lat ~410):
//     predicted 83 us = observed 83 us. Model confirmed; nt-gather reverted.
// R7: A/B test: product layers gather with sc0 (GLC: L1-bypass, L2-cached,
//     possibly non-fill path => more concurrency); sum layers = exact R3.

#define LOG2F 0.6931471805599453f

typedef int iv4 __attribute__((ext_vector_type(4)));

__global__ void encode_kernel(const float* __restrict__ pos,
                              __half* __restrict__ x0, int n) {
    int i = blockIdx.x * blockDim.x + threadIdx.x;
    if (i == 0) { x0[0] = __float2half(-INFINITY); x0[1] = __float2half(0.0f); }
    if (i < n) {
        float p = pos[i];
        // log1mexp (Maechler 2012), stable for p < 0
        float neg = (p > -LOG2F) ? logf(-expm1f(p)) : log1pf(-expf(p));
        __half2 v; v.x = __float2half(p); v.y = __float2half(neg);
        ((__half2*)(x0 + 2))[i] = v;  // interleaved pos/neg
    }
}

// ---- product: sc0 (GLC) gathers — L1-bypass, L2-allocating ----
__global__ void product_kernel(const __half* __restrict__ x,
                               const iv4* __restrict__ ptrs,
                               __half* __restrict__ out, int m) {
    int i = blockIdx.x * blockDim.x + threadIdx.x;
    if (i < m) {
        iv4 q = __builtin_nontemporal_load(&ptrs[i]);  // idx stream: touched once
        const unsigned short* t = (const unsigned short*)x;
        unsigned int r0, r1, r2, r3;
        const unsigned short* a0 = t + q.x;
        const unsigned short* a1 = t + q.y;
        const unsigned short* a2 = t + q.z;
        const unsigned short* a3 = t + q.w;
        asm volatile(
            "global_load_ushort %0, %4, off sc0\n\t"
            "global_load_ushort %1, %5, off sc0\n\t"
            "global_load_ushort %2, %6, off sc0\n\t"
            "global_load_ushort %3, %7, off sc0\n\t"
            "s_waitcnt vmcnt(0)"
            : "=&v"(r0), "=&v"(r1), "=&v"(r2), "=&v"(r3)
            : "v"(a0), "v"(a1), "v"(a2), "v"(a3)
            : "memory");
        float s = __half2float(__ushort_as_half((unsigned short)r0))
                + __half2float(__ushort_as_half((unsigned short)r1))
                + __half2float(__ushort_as_half((unsigned short)r2))
                + __half2float(__ushort_as_half((unsigned short)r3));
        __builtin_nontemporal_store(__half_as_short(__float2half(s)),
                                    (short*)&out[i]);
    }
}

__device__ __forceinline__ float lse4(float a, float b, float c, float d) {
    float mx = fmaxf(fmaxf(a, b), fmaxf(c, d));
    if (mx == -INFINITY) return -INFINITY;  // ref: exps nan->0, log(eps)+(-inf)
    float s = expf(a - mx) + expf(b - mx) + expf(c - mx) + expf(d - mx) + 1e-15f;
    return logf(s) + mx;
}

// ---- sum: exact R3 gathers (plain, L1+L2 cached) ----
template <typename OutT>
__global__ void sum_kernel(const __half* __restrict__ x,
                           const iv4* __restrict__ ptrs,
                           OutT* __restrict__ out, int m) {
    int i = blockIdx.x * blockDim.x + threadIdx.x;
    if (i < m) {
        iv4 q = __builtin_nontemporal_load(&ptrs[i]);
        float a = __half2float(x[q.x]), b = __half2float(x[q.y]);
        float c = __half2float(x[q.z]), d = __half2float(x[q.w]);
        float r = lse4(a, b, c, d);
        if constexpr (sizeof(OutT) == 2) {
            __builtin_nontemporal_store(__half_as_short(__float2half(r)),
                                        (short*)&out[i]);
        } else {
            __builtin_nontemporal_store(r, (float*)&out[i]);
        }
    }
}

extern "C" void kernel_launch(void* const* d_in, const int* in_sizes, int n_in,
                              void* d_out, int out_size, void* d_ws, size_t ws_size,
                              hipStream_t stream) {
    const float* pos = (const float*)d_in[0];
    const iv4*   p0  = (const iv4*)d_in[1];
    const iv4*   p1  = (const iv4*)d_in[2];
    const iv4*   p2  = (const iv4*)d_in[3];
    const iv4*   p3  = (const iv4*)d_in[4];
    // d_in[5] is csr — structurally repeat(arange(M),4), not needed.

    const int N = in_sizes[0];      // 1,000,000
    const int M = out_size;         // 2,000,000

    char* ws = (char*)d_ws;
    size_t s0_bytes = ((((size_t)2 * N + 2) * sizeof(__half)) + 255) & ~(size_t)255;
    size_t m_bytes  = (((size_t)M * sizeof(__half)) + 255) & ~(size_t)255;
    __half* x0 = (__half*)ws;                          // encoded input [2N+2] fp16
    __half* x1 = (__half*)(ws + s0_bytes);             // layer scratch [M] fp16
    __half* x2 = (__half*)(ws + s0_bytes + m_bytes);   // layer scratch [M] fp16
    float* outp = (float*)d_out;                       // final output fp32

    const int blk = 256;
    const int gN = (N + blk - 1) / blk;
    const int gM = (M + blk - 1) / blk;

    encode_kernel     <<<gN, blk, 0, stream>>>(pos, x0, N);
    product_kernel    <<<gM, blk, 0, stream>>>(x0, p0, x1, M);
    sum_kernel<__half><<<gM, blk, 0, stream>>>(x1, p1, x2, M);
    product_kernel    <<<gM, blk, 0, stream>>>(x2, p2, x1, M);
    sum_kernel<float> <<<gM, blk, 0, stream>>>(x1, p3, outp, M);
}